// Round 5
// baseline (2688.401 us; speedup 1.0000x reference)
//
#include <hip/hip_runtime.h>
#include <math.h>

#define NEG_SLOPE 0.2f
#define FIN 128
#define H1 8
#define F1 64   // HEADS1*HID
#define F2 32   // OUT2

#define SHIFT 6
#define BW 64          // dsts per bucket
#define CAPE 3072      // max edges per bucket in LDS (avg ~2112, sigma ~46)
#define CH1 512        // edge1 weight-chunk
#define NBMAX 2048

typedef unsigned short ushort_t;
typedef unsigned int uint_t;

static __device__ __forceinline__ ushort_t f2bf(float f) {
    uint_t u = __float_as_uint(f);
    u = (u + 0x7FFFu + ((u >> 16) & 1u)) >> 16; // RNE
    return (ushort_t)u;
}
static __device__ __forceinline__ float bf2f(ushort_t h) {
    return __uint_as_float(((uint_t)h) << 16);
}

// ---------------- Layer-1 GEMM: h1 = x @ W1 (bf16 out), fused e_src/e_dst ----
// block = 256 thr, 32 nodes; W1 + x staged in LDS; 4-node register blocking
__global__ void gemm1_kernel(const float* __restrict__ x, const float* __restrict__ W1,
                             const float* __restrict__ a_src, const float* __restrict__ a_dst,
                             ushort_t* __restrict__ h1, float* __restrict__ es, float* __restrict__ ed,
                             int N) {
    __shared__ float w1s[FIN * F1];   // 32 KB
    __shared__ float xss[32][FIN];    // 16 KB
    int tid = threadIdx.x;
    int n0 = blockIdx.x * 32;
    for (int i = tid; i < FIN * F1; i += 256) w1s[i] = W1[i];
    for (int i = tid; i < 32 * FIN; i += 256) {
        int nn = n0 + (i >> 7);
        xss[i >> 7][i & 127] = (nn < N) ? x[(size_t)nn * FIN + (i & 127)] : 0.f;
    }
    __syncthreads();
    int wv = tid >> 6, j = tid & 63;
    float as = a_src[j], ad = a_dst[j];
#pragma unroll
    for (int g = 0; g < 2; ++g) {
        int nb = (wv << 3) + (g << 2);
        float a0 = 0.f, a1 = 0.f, a2 = 0.f, a3 = 0.f;
        for (int k = 0; k < FIN; k += 4) {
            float4 x0 = *(const float4*)&xss[nb + 0][k];
            float4 x1 = *(const float4*)&xss[nb + 1][k];
            float4 x2 = *(const float4*)&xss[nb + 2][k];
            float4 x3 = *(const float4*)&xss[nb + 3][k];
            float w0 = w1s[k * 64 + j], w1 = w1s[(k + 1) * 64 + j];
            float w2 = w1s[(k + 2) * 64 + j], w3 = w1s[(k + 3) * 64 + j];
            a0 = fmaf(x0.x, w0, fmaf(x0.y, w1, fmaf(x0.z, w2, fmaf(x0.w, w3, a0))));
            a1 = fmaf(x1.x, w0, fmaf(x1.y, w1, fmaf(x1.z, w2, fmaf(x1.w, w3, a1))));
            a2 = fmaf(x2.x, w0, fmaf(x2.y, w1, fmaf(x2.z, w2, fmaf(x2.w, w3, a2))));
            a3 = fmaf(x3.x, w0, fmaf(x3.y, w1, fmaf(x3.z, w2, fmaf(x3.w, w3, a3))));
        }
        float av[4] = {a0, a1, a2, a3};
#pragma unroll
        for (int t = 0; t < 4; ++t) {
            int nn = n0 + nb + t;
            if (nn >= N) continue;
            h1[(size_t)nn * F1 + j] = f2bf(av[t]);
            float vs = av[t] * as, vd = av[t] * ad;
#pragma unroll
            for (int off = 4; off >= 1; off >>= 1) {
                vs += __shfl_down(vs, off, 8);
                vd += __shfl_down(vd, off, 8);
            }
            if ((j & 7) == 0) {
                es[nn * H1 + (j >> 3)] = vs;
                ed[nn * H1 + (j >> 3)] = vd;
            }
        }
    }
}

// ---------------- bucket CSR build ------------------------------------------
__global__ void zerob_kernel(int* __restrict__ bcnt, int NB, float* __restrict__ pooled) {
    int t = blockIdx.x * blockDim.x + threadIdx.x;
    int stride = gridDim.x * blockDim.x;
    for (int i = t; i < NB; i += stride) bcnt[i] = 0;
    if (t == 0) pooled[0] = 0.f;
}

__global__ void bhist_kernel(const int* __restrict__ ei, int E, int N,
                             int* __restrict__ bcnt, int NB) {
    __shared__ int h[NBMAX];
    int tid = threadIdx.x;
    for (int i = tid; i < NB; i += 256) h[i] = 0;
    __syncthreads();
    int EN = E + N;
    int chunk = (EN + gridDim.x - 1) / gridDim.x;
    int e0 = blockIdx.x * chunk;
    int e1 = e0 + chunk; if (e1 > EN) e1 = EN;
    for (int t = e0 + tid; t < e1; t += 256) {
        int d = (t < E) ? ei[E + t] : (t - E);
        atomicAdd(&h[d >> SHIFT], 1);
    }
    __syncthreads();
    for (int i = tid; i < NB; i += 256)
        if (h[i]) atomicAdd(&bcnt[i], h[i]);
}

__global__ void bscan_kernel(const int* __restrict__ bcnt, int NB,
                             int* __restrict__ boff, int* __restrict__ bcur) {
    int lane = threadIdx.x; // 0..63
    int chunk = (NB + 63) >> 6;
    int lo = lane * chunk;
    int hi = lo + chunk; if (hi > NB) hi = NB;
    int sum = 0;
    for (int i = lo; i < hi; ++i) sum += bcnt[i];
    int e = sum;
#pragma unroll
    for (int o = 1; o < 64; o <<= 1) {
        int v = __shfl_up(e, o, 64);
        if (lane >= o) e += v;
    }
    e -= sum;
    int run = e;
    for (int i = lo; i < hi; ++i) {
        int c = bcnt[i];
        boff[i] = run;
        bcur[i] = run;
        run += c;
    }
}

__global__ void bscat_kernel(const int* __restrict__ ei, int E, int N,
                             int* __restrict__ bcur, uint_t* __restrict__ pk, int NB) {
    __shared__ int lh[NBMAX];
    __shared__ int lc[NBMAX];
    int tid = threadIdx.x;
    for (int i = tid; i < NB; i += 256) lh[i] = 0;
    __syncthreads();
    int EN = E + N;
    int chunk = (EN + gridDim.x - 1) / gridDim.x;
    int e0 = blockIdx.x * chunk;
    int e1 = e0 + chunk; if (e1 > EN) e1 = EN;
    for (int t = e0 + tid; t < e1; t += 256) {
        int d = (t < E) ? ei[E + t] : (t - E);
        atomicAdd(&lh[d >> SHIFT], 1);
    }
    __syncthreads();
    for (int i = tid; i < NB; i += 256) {
        int c = lh[i];
        lc[i] = c ? atomicAdd(&bcur[i], c) : 0;
    }
    __syncthreads();
    for (int t = e0 + tid; t < e1; t += 256) {
        int s, d;
        if (t < E) { s = ei[t]; d = ei[E + t]; } else { s = d = t - E; }
        int pos = atomicAdd(&lc[d >> SHIFT], 1);
        pk[pos] = ((uint_t)s << SHIFT) | (uint_t)(d & (BW - 1));
    }
}

// ---------------- Layer-1 edge pass ------------------------------------------
// one block per bucket. Phase A (per 512-edge chunk): weights once per
// (edge,head) into lw. Phase B: wave per dst (stride-4 interleave), 2 edges
// per iteration (half-wave each), 2 channels per lane (bf16x2).
__global__ void edge1_gather(const int* __restrict__ bcnt, const int* __restrict__ boff,
                             const uint_t* __restrict__ pk,
                             const float* __restrict__ es, const float* __restrict__ ed,
                             const ushort_t* __restrict__ h1, float* __restrict__ o1, int N) {
    int b = blockIdx.x;
    int d0 = b << SHIFT;
    int cnt = bcnt[b];
    int gbase = boff[b];
    int tid = threadIdx.x;
    int wv = tid >> 6;
    int L = tid & 63;
    int eh = L >> 5;     // edge slot 0/1
    int jj = L & 31;     // channel-pair index
    int ch = jj << 1;    // channels ch, ch+1
    int h = jj >> 2;     // head of both channels
    __shared__ int ldeg[BW], loff[BW], lcur[BW];
    __shared__ uint_t lsrc[CAPE];
    __shared__ float lw[CH1 * 8];
    __shared__ float edl[BW * H1];
    for (int i = tid; i < BW * H1; i += 256) {
        int g = (d0 << 3) + i;
        edl[i] = (g < N * H1) ? ed[g] : 0.f;
    }
    if (tid < BW) ldeg[tid] = 0;
    __syncthreads();
    float2 acc[16];
    float wsm[16];
#pragma unroll
    for (int q = 0; q < 16; ++q) { acc[q].x = 0.f; acc[q].y = 0.f; wsm[q] = 0.f; }
    if (cnt <= CAPE) {
        for (int k = tid; k < cnt; k += 256) atomicAdd(&ldeg[pk[gbase + k] & (BW - 1)], 1);
        __syncthreads();
        if (tid < 64) {
            int v = ldeg[tid]; int e = v;
#pragma unroll
            for (int o = 1; o < 64; o <<= 1) {
                int u = __shfl_up(e, o, 64);
                if (tid >= o) e += u;
            }
            e -= v;
            loff[tid] = e;
            lcur[tid] = e;
        }
        __syncthreads();
        for (int k = tid; k < cnt; k += 256) {
            uint_t v = pk[gbase + k];
            int p = atomicAdd(&lcur[v & (BW - 1)], 1);
            lsrc[p] = v;
        }
        __syncthreads();
        for (int cb = 0; cb < cnt; cb += CH1) {
            int ce = (cnt < cb + CH1) ? cnt : cb + CH1;
            int cs = ce - cb;
            // phase A: one weight per (edge, head)
            for (int i = tid; i < (cs << 3); i += 256) {
                int k = i >> 3, hh = i & 7;
                uint_t v = lsrc[cb + k];
                int s = (int)(v >> SHIFT), ld = (int)(v & (BW - 1));
                float t = es[s * H1 + hh] + edl[ld * H1 + hh];
                t = t > 0.f ? t : t * NEG_SLOPE;
                lw[i] = __expf(t);
            }
            __syncthreads();
            // phase B
#pragma unroll
            for (int q = 0; q < 16; ++q) {
                int ld = (q << 2) + wv;
                int st = loff[ld], en = st + ldeg[ld];
                int lo = st > cb ? st : cb;
                int hi = en < ce ? en : ce;
                for (int k = lo; k < hi; k += 2) {
                    int idx = k + eh;
                    int ok = idx < hi;
                    uint_t v = lsrc[ok ? idx : k];
                    int s = (int)(v >> SHIFT);
                    float w = ok ? lw[((idx - cb) << 3) + h] : 0.f;
                    uint_t hv = *(const uint_t*)(h1 + (size_t)s * F1 + ch);
                    acc[q].x = fmaf(w, __uint_as_float(hv << 16), acc[q].x);
                    acc[q].y = fmaf(w, __uint_as_float(hv & 0xffff0000u), acc[q].y);
                    wsm[q] += w;
                }
            }
            __syncthreads();
        }
    } else {
        // statistically unreachable fallback: scan whole bucket from global pk
        for (int k0 = 0; k0 < cnt; k0 += 2) {
            int idx = k0 + eh;
            int ok0 = idx < cnt;
            uint_t v = pk[gbase + (ok0 ? idx : k0)];
            int s = (int)(v >> SHIFT);
            int vld = (int)(v & (BW - 1));
            float t = es[s * H1 + h] + edl[vld * H1 + h];
            t = t > 0.f ? t : t * NEG_SLOPE;
            float w = __expf(t);
            uint_t hv = *(const uint_t*)(h1 + (size_t)s * F1 + ch);
            float f0 = __uint_as_float(hv << 16);
            float f1 = __uint_as_float(hv & 0xffff0000u);
#pragma unroll
            for (int q = 0; q < 16; ++q) {
                int ld = (q << 2) + wv;
                float wq = (ok0 && vld == ld) ? w : 0.f;
                acc[q].x = fmaf(wq, f0, acc[q].x);
                acc[q].y = fmaf(wq, f1, acc[q].y);
                wsm[q] += wq;
            }
        }
    }
    // epilogue: combine halves, normalize, write
#pragma unroll
    for (int q = 0; q < 16; ++q) {
        int d = d0 + (q << 2) + wv;
        float ax = acc[q].x + __shfl_xor(acc[q].x, 32, 64);
        float ay = acc[q].y + __shfl_xor(acc[q].y, 32, 64);
        float ws = wsm[q] + __shfl_xor(wsm[q], 32, 64);
        if (d < N && eh == 0) {
            float inv = 1.f / ws;   // self-loop => ws > 0
            float2 r; r.x = ax * inv; r.y = ay * inv;
            *(float2*)(o1 + (size_t)d * F1 + ch) = r;
        }
    }
}

// ---------------- Layer-2 GEMM: a1 = elu(o1 + b1); h2 = a1 @ W2 (bf16) -------
__global__ void gemm2_kernel(const float* __restrict__ o1, const float* __restrict__ b1,
                             const float* __restrict__ W2,
                             const float* __restrict__ a_src2, const float* __restrict__ a_dst2,
                             ushort_t* __restrict__ h2, float* __restrict__ es2,
                             float* __restrict__ ed2, int N) {
    int half = threadIdx.x >> 5;
    int n = blockIdx.x * 8 + half;
    int j = threadIdx.x & 31;
    __shared__ float a1s[8][F1];
    if (n < N) {
#pragma unroll
        for (int r = 0; r < 2; ++r) {
            int k = r * 32 + j;
            float v = o1[(size_t)n * F1 + k] + b1[k];
            a1s[half][k] = v > 0.f ? v : expm1f(v); // ELU
        }
    }
    __syncthreads();
    if (n >= N) return;
    float acc = 0.f;
#pragma unroll
    for (int k = 0; k < F1; ++k) acc = fmaf(a1s[half][k], W2[k * F2 + j], acc);
    h2[(size_t)n * F2 + j] = f2bf(acc);
    float vs = acc * a_src2[j];
    float vd = acc * a_dst2[j];
#pragma unroll
    for (int off = 16; off >= 1; off >>= 1) {
        vs += __shfl_down(vs, off, 32);
        vd += __shfl_down(vd, off, 32);
    }
    if (j == 0) { es2[n] = vs; ed2[n] = vd; }
}

// ---------------- Layer-2 edge pass ------------------------------------------
// phase A: weight once per edge into lw2 (full bucket). Phase B: wave per dst
// (stride-4), 2 edges/iter (half-wave each, 32 channels). Fused pool·Wr.
__global__ void edge2_gather(const int* __restrict__ bcnt, const int* __restrict__ boff,
                             const uint_t* __restrict__ pk,
                             const float* __restrict__ es, const float* __restrict__ ed,
                             const ushort_t* __restrict__ h2,
                             const float* __restrict__ b2, const float* __restrict__ Wr,
                             float* __restrict__ pooled, int N) {
    int b = blockIdx.x;
    int d0 = b << SHIFT;
    int cnt = bcnt[b];
    int gbase = boff[b];
    int tid = threadIdx.x;
    int wv = tid >> 6;
    int L = tid & 63;
    int eh = L >> 5;
    int ch = L & 31;
    __shared__ int ldeg[BW], loff[BW], lcur[BW];
    __shared__ uint_t lsrc[CAPE];
    __shared__ float lw2[CAPE];
    __shared__ float edl[BW];
    if (tid < BW) {
        int d = d0 + tid;
        edl[tid] = (d < N) ? ed[d] : 0.f;
        ldeg[tid] = 0;
    }
    __syncthreads();
    float accq[16], wsm[16];
#pragma unroll
    for (int q = 0; q < 16; ++q) { accq[q] = 0.f; wsm[q] = 0.f; }
    float wr = Wr[ch];
    float b2w = b2[ch] * wr;
    if (cnt <= CAPE) {
        for (int k = tid; k < cnt; k += 256) atomicAdd(&ldeg[pk[gbase + k] & (BW - 1)], 1);
        __syncthreads();
        if (tid < 64) {
            int v = ldeg[tid]; int e = v;
#pragma unroll
            for (int o = 1; o < 64; o <<= 1) {
                int u = __shfl_up(e, o, 64);
                if (tid >= o) e += u;
            }
            e -= v;
            loff[tid] = e;
            lcur[tid] = e;
        }
        __syncthreads();
        for (int k = tid; k < cnt; k += 256) {
            uint_t v = pk[gbase + k];
            int p = atomicAdd(&lcur[v & (BW - 1)], 1);
            lsrc[p] = v;
        }
        __syncthreads();
        for (int i = tid; i < cnt; i += 256) {
            uint_t v = lsrc[i];
            int s = (int)(v >> SHIFT), ld = (int)(v & (BW - 1));
            float t = es[s] + edl[ld];
            t = t > 0.f ? t : t * NEG_SLOPE;
            lw2[i] = __expf(t);
        }
        __syncthreads();
#pragma unroll
        for (int q = 0; q < 16; ++q) {
            int ld = (q << 2) + wv;
            int st = loff[ld], en = st + ldeg[ld];
            for (int k = st; k < en; k += 2) {
                int idx = k + eh;
                int ok = idx < en;
                uint_t v = lsrc[ok ? idx : k];
                int s = (int)(v >> SHIFT);
                float w = ok ? lw2[idx] : 0.f;
                accq[q] = fmaf(w, bf2f(h2[(size_t)s * F2 + ch]), accq[q]);
                wsm[q] += w;
            }
        }
    } else {
        for (int k0 = 0; k0 < cnt; k0 += 2) {
            int idx = k0 + eh;
            int ok0 = idx < cnt;
            uint_t v = pk[gbase + (ok0 ? idx : k0)];
            int s = (int)(v >> SHIFT);
            int vld = (int)(v & (BW - 1));
            float t = es[s] + edl[vld];
            t = t > 0.f ? t : t * NEG_SLOPE;
            float w = __expf(t);
            float hv = bf2f(h2[(size_t)s * F2 + ch]);
#pragma unroll
            for (int q = 0; q < 16; ++q) {
                int ld = (q << 2) + wv;
                float wq = (ok0 && vld == ld) ? w : 0.f;
                accq[q] = fmaf(wq, hv, accq[q]);
                wsm[q] += wq;
            }
        }
    }
    float part = 0.f;
#pragma unroll
    for (int q = 0; q < 16; ++q) {
        int d = d0 + (q << 2) + wv;
        float a = accq[q] + __shfl_xor(accq[q], 32, 64);
        float ws = wsm[q] + __shfl_xor(wsm[q], 32, 64);
        if (d < N && eh == 0) part += fmaf(a / ws, wr, b2w);
    }
#pragma unroll
    for (int o = 32; o >= 1; o >>= 1) part += __shfl_down(part, o, 64);
    __shared__ float ls[4];
    int wave = tid >> 6;
    if ((tid & 63) == 0) ls[wave] = part;
    __syncthreads();
    if (tid == 0) atomicAdd(pooled, ls[0] + ls[1] + ls[2] + ls[3]);
}

__global__ void final_kernel(const float* __restrict__ pooled, const float* __restrict__ br,
                             float* __restrict__ out) {
    if (threadIdx.x == 0 && blockIdx.x == 0) out[0] = pooled[0] + br[0];
}

extern "C" void kernel_launch(void* const* d_in, const int* in_sizes, int n_in,
                              void* d_out, int out_size, void* d_ws, size_t ws_size,
                              hipStream_t stream) {
    const float* x    = (const float*)d_in[0];
    const int*   ei   = (const int*)d_in[1];
    const float* W1   = (const float*)d_in[2];
    const float* a_s1 = (const float*)d_in[3];
    const float* a_d1 = (const float*)d_in[4];
    const float* b1   = (const float*)d_in[5];
    const float* W2   = (const float*)d_in[6];
    const float* a_s2 = (const float*)d_in[7];
    const float* a_d2 = (const float*)d_in[8];
    const float* b2   = (const float*)d_in[9];
    const float* Wr   = (const float*)d_in[10];
    const float* br   = (const float*)d_in[11];
    float* out = (float*)d_out;

    int N = in_sizes[0] / FIN;
    int E = in_sizes[1] / 2;
    size_t n = (size_t)N;
    int NB = (N + BW - 1) >> SHIFT;

    // workspace layout (bytes), total ~= 58 MB for N=100k, E=3.2M
    char* ws = (char*)d_ws;
    float*    o1   = (float*)ws;                          // 64N f32
    float*    es1  = (float*)(ws + n * 256);              // 8N f32
    float*    ed1  = (float*)(ws + n * 288);              // 8N f32
    ushort_t* h1   = (ushort_t*)(ws + n * 320);           // 64N bf16
    uint_t*   pk   = (uint_t*)(ws + n * 448);             // (E+N) uint
    char*     tail = ws + n * 448 + (size_t)(E + N) * 4;
    int*      bcnt = (int*)tail;                          // NBMAX int
    int*      boff = (int*)(tail + NBMAX * 4);            // NBMAX int
    int*      bcur = (int*)(tail + NBMAX * 8);            // NBMAX int
    float*  pooled = (float*)(tail + NBMAX * 12);         // 1 f32
    // layer-2 overlays (regions dead after edge1):
    ushort_t* h2  = h1;      // 32N bf16
    float*    es2 = es1;     // N f32
    float*    ed2 = ed1;     // N f32

    zerob_kernel<<<8, 256, 0, stream>>>(bcnt, NB, pooled);
    gemm1_kernel<<<(N + 31) / 32, 256, 0, stream>>>(x, W1, a_s1, a_d1, h1, es1, ed1, N);
    bhist_kernel<<<256, 256, 0, stream>>>(ei, E, N, bcnt, NB);
    bscan_kernel<<<1, 64, 0, stream>>>(bcnt, NB, boff, bcur);
    bscat_kernel<<<64, 256, 0, stream>>>(ei, E, N, bcur, pk, NB);
    edge1_gather<<<NB, 256, 0, stream>>>(bcnt, boff, pk, es1, ed1, h1, o1, N);
    gemm2_kernel<<<(N + 7) / 8, 256, 0, stream>>>(o1, b1, W2, a_s2, a_d2, h2, es2, ed2, N);
    edge2_gather<<<NB, 256, 0, stream>>>(bcnt, boff, pk, es2, ed2, h2, b2, Wr, pooled, N);
    final_kernel<<<1, 64, 0, stream>>>(pooled, br, out);
}

// Round 6
// 537.403 us; speedup vs baseline: 5.0026x; 5.0026x over previous
//
#include <hip/hip_runtime.h>
#include <math.h>

#define NEG_SLOPE 0.2f
#define FIN 128
#define H1 8
#define F1 64   // HEADS1*HID
#define F2 32   // OUT2

#define SHIFT 6
#define BW 64          // dsts per bucket
#define CAP 4096       // max edges per bucket in LDS (avg ~2112, sigma ~46)
#define NBMAX 2048

typedef unsigned short ushort_t;
typedef unsigned int uint_t;

static __device__ __forceinline__ ushort_t f2bf(float f) {
    uint_t u = __float_as_uint(f);
    u = (u + 0x7FFFu + ((u >> 16) & 1u)) >> 16; // RNE
    return (ushort_t)u;
}
static __device__ __forceinline__ float bf2f(ushort_t h) {
    return __uint_as_float(((uint_t)h) << 16);
}
// pack {A=exp(e), B=exp(0.2e)} as bf16x2: A in low 16, B in high 16
static __device__ __forceinline__ uint_t packAB(float e) {
    return (uint_t)f2bf(__expf(e)) | ((uint_t)f2bf(__expf(NEG_SLOPE * e)) << 16);
}

// ---------------- Layer-1 GEMM: h1 = x @ W1 (bf16 out), fused exp-tables -----
// round-4 proven structure: 4 nodes/block, one wave per node, xs in LDS
__global__ void gemm1_kernel(const float* __restrict__ x, const float* __restrict__ W1,
                             const float* __restrict__ a_src, const float* __restrict__ a_dst,
                             ushort_t* __restrict__ h1, uint_t* __restrict__ sp,
                             float* __restrict__ ed, int N) {
    int w = threadIdx.x >> 6;
    int j = threadIdx.x & 63;
    int n = blockIdx.x * 4 + w;
    __shared__ float xs[4][FIN];
    if (n < N) {
        xs[w][j]      = x[(size_t)n * FIN + j];
        xs[w][j + 64] = x[(size_t)n * FIN + 64 + j];
    }
    // wave-synchronous LDS (same wave writes & reads)
    if (n >= N) return;
    float acc = 0.f;
#pragma unroll
    for (int k = 0; k < FIN; ++k) acc = fmaf(xs[w][k], W1[k * F1 + j], acc);
    h1[(size_t)n * F1 + j] = f2bf(acc);
    float vs = acc * a_src[j];
    float vd = acc * a_dst[j];
#pragma unroll
    for (int off = 4; off >= 1; off >>= 1) {
        vs += __shfl_down(vs, off, 8);
        vd += __shfl_down(vd, off, 8);
    }
    if ((j & 7) == 0) {
        sp[n * H1 + (j >> 3)] = packAB(vs);   // src-side exp table (bf16x2)
        ed[n * H1 + (j >> 3)] = vd;           // raw dst logit
    }
}

// ---------------- bucket CSR build ------------------------------------------
__global__ void zerob_kernel(int* __restrict__ bcnt, int NB, float* __restrict__ pooled) {
    int t = blockIdx.x * blockDim.x + threadIdx.x;
    int stride = gridDim.x * blockDim.x;
    for (int i = t; i < NB; i += stride) bcnt[i] = 0;
    if (t == 0) pooled[0] = 0.f;
}

__global__ void bhist_kernel(const int* __restrict__ ei, int E, int N,
                             int* __restrict__ bcnt, int NB) {
    __shared__ int h[NBMAX];
    int tid = threadIdx.x;
    for (int i = tid; i < NB; i += 256) h[i] = 0;
    __syncthreads();
    int EN = E + N;
    int chunk = (EN + gridDim.x - 1) / gridDim.x;
    int e0 = blockIdx.x * chunk;
    int e1 = e0 + chunk; if (e1 > EN) e1 = EN;
    for (int t = e0 + tid; t < e1; t += 256) {
        int d = (t < E) ? ei[E + t] : (t - E);
        atomicAdd(&h[d >> SHIFT], 1);
    }
    __syncthreads();
    for (int i = tid; i < NB; i += 256)
        if (h[i]) atomicAdd(&bcnt[i], h[i]);
}

__global__ void bscan_kernel(const int* __restrict__ bcnt, int NB,
                             int* __restrict__ boff, int* __restrict__ bcur) {
    int lane = threadIdx.x; // 0..63
    int chunk = (NB + 63) >> 6;
    int lo = lane * chunk;
    int hi = lo + chunk; if (hi > NB) hi = NB;
    int sum = 0;
    for (int i = lo; i < hi; ++i) sum += bcnt[i];
    int e = sum;
#pragma unroll
    for (int o = 1; o < 64; o <<= 1) {
        int v = __shfl_up(e, o, 64);
        if (lane >= o) e += v;
    }
    e -= sum;
    int run = e;
    for (int i = lo; i < hi; ++i) {
        int c = bcnt[i];
        boff[i] = run;
        bcur[i] = run;
        run += c;
    }
}

__global__ void bscat_kernel(const int* __restrict__ ei, int E, int N,
                             int* __restrict__ bcur, uint_t* __restrict__ pk, int NB) {
    __shared__ int lh[NBMAX];
    __shared__ int lc[NBMAX];
    int tid = threadIdx.x;
    for (int i = tid; i < NB; i += 256) lh[i] = 0;
    __syncthreads();
    int EN = E + N;
    int chunk = (EN + gridDim.x - 1) / gridDim.x;
    int e0 = blockIdx.x * chunk;
    int e1 = e0 + chunk; if (e1 > EN) e1 = EN;
    for (int t = e0 + tid; t < e1; t += 256) {
        int d = (t < E) ? ei[E + t] : (t - E);
        atomicAdd(&lh[d >> SHIFT], 1);
    }
    __syncthreads();
    for (int i = tid; i < NB; i += 256) {
        int c = lh[i];
        lc[i] = c ? atomicAdd(&bcur[i], c) : 0;
    }
    __syncthreads();
    for (int t = e0 + tid; t < e1; t += 256) {
        int s, d;
        if (t < E) { s = ei[t]; d = ei[E + t]; } else { s = d = t - E; }
        int pos = atomicAdd(&lc[d >> SHIFT], 1);
        pk[pos] = ((uint_t)s << SHIFT) | (uint_t)(d & (BW - 1));
    }
}

// ---------------- Layer-1 edge pass: LDS-CSR gather, exp-free inner loop -----
// one block per bucket (64 dsts); wave w handles 16 dsts; lane j = channel
__global__ void edge1_gather(const int* __restrict__ bcnt, const int* __restrict__ boff,
                             const uint_t* __restrict__ pk,
                             const uint_t* __restrict__ sp, const float* __restrict__ ed,
                             const ushort_t* __restrict__ h1, float* __restrict__ o1, int N) {
    int b = blockIdx.x;
    int d0 = b << SHIFT;
    int cnt = bcnt[b];
    int gbase = boff[b];
    int tid = threadIdx.x;
    int wv = tid >> 6;
    int j = tid & 63;
    int hB = j >> 3;
    __shared__ int ldeg[BW];
    __shared__ int loff[BW];
    __shared__ int lcur[BW];
    __shared__ int lsrc[CAP];
    if (cnt <= CAP) {
        if (tid < BW) ldeg[tid] = 0;
        __syncthreads();
        for (int k = tid; k < cnt; k += 256) atomicAdd(&ldeg[pk[gbase + k] & (BW - 1)], 1);
        __syncthreads();
        if (tid < 64) {
            int v = ldeg[tid];
            int e = v;
#pragma unroll
            for (int o = 1; o < 64; o <<= 1) {
                int u = __shfl_up(e, o, 64);
                if (tid >= o) e += u;
            }
            e -= v;
            loff[tid] = e;
            lcur[tid] = e;
        }
        __syncthreads();
        for (int k = tid; k < cnt; k += 256) {
            uint_t v = pk[gbase + k];
            int pos = atomicAdd(&lcur[v & (BW - 1)], 1);
            lsrc[pos] = (int)(v >> SHIFT);
        }
        __syncthreads();
        for (int ld = wv * 16; ld < wv * 16 + 16; ++ld) {
            int d = d0 + ld;
            if (d >= N) break;
            int st = loff[ld], dg = ldeg[ld];
            float edv = ed[d * H1 + hB];
            float Ad = __expf(edv), Bd = __expf(NEG_SLOPE * edv);
            float acc = 0.f, wsum = 0.f;
#pragma unroll 4
            for (int k = st; k < st + dg; ++k) {
                int s = lsrc[k];
                uint_t u = sp[s * H1 + hB];
                float w = fmaxf(__uint_as_float(u << 16) * Ad,
                                __uint_as_float(u & 0xffff0000u) * Bd);
                acc = fmaf(w, bf2f(h1[(size_t)s * F1 + j]), acc);
                wsum += w;
            }
            o1[(size_t)d * F1 + j] = acc / wsum; // self-loop => wsum > 0
        }
    } else {
        // statistically unreachable fallback: scan whole bucket per dst
        for (int ld = wv * 16; ld < wv * 16 + 16; ++ld) {
            int d = d0 + ld;
            if (d >= N) break;
            float edv = ed[d * H1 + hB];
            float Ad = __expf(edv), Bd = __expf(NEG_SLOPE * edv);
            float acc = 0.f, wsum = 0.f;
            for (int k = 0; k < cnt; ++k) {
                uint_t v = pk[gbase + k];
                if ((int)(v & (BW - 1)) != ld) continue;
                int s = (int)(v >> SHIFT);
                uint_t u = sp[s * H1 + hB];
                float w = fmaxf(__uint_as_float(u << 16) * Ad,
                                __uint_as_float(u & 0xffff0000u) * Bd);
                acc = fmaf(w, bf2f(h1[(size_t)s * F1 + j]), acc);
                wsum += w;
            }
            o1[(size_t)d * F1 + j] = acc / wsum;
        }
    }
}

// ---------------- Layer-2 GEMM: a1 = elu(o1 + b1); h2 = a1 @ W2 (bf16) -------
__global__ void gemm2_kernel(const float* __restrict__ o1, const float* __restrict__ b1,
                             const float* __restrict__ W2,
                             const float* __restrict__ a_src2, const float* __restrict__ a_dst2,
                             ushort_t* __restrict__ h2, uint_t* __restrict__ sp2,
                             float* __restrict__ ed2, int N) {
    int half = threadIdx.x >> 5;
    int n = blockIdx.x * 8 + half;
    int j = threadIdx.x & 31;
    __shared__ float a1s[8][F1];
    if (n < N) {
#pragma unroll
        for (int r = 0; r < 2; ++r) {
            int k = r * 32 + j;
            float v = o1[(size_t)n * F1 + k] + b1[k];
            a1s[half][k] = v > 0.f ? v : expm1f(v); // ELU
        }
    }
    __syncthreads();
    if (n >= N) return;
    float acc = 0.f;
#pragma unroll
    for (int k = 0; k < F1; ++k) acc = fmaf(a1s[half][k], W2[k * F2 + j], acc);
    h2[(size_t)n * F2 + j] = f2bf(acc);
    float vs = acc * a_src2[j];
    float vd = acc * a_dst2[j];
#pragma unroll
    for (int off = 16; off >= 1; off >>= 1) {
        vs += __shfl_down(vs, off, 32);
        vd += __shfl_down(vd, off, 32);
    }
    if (j == 0) {
        sp2[n] = packAB(vs);
        ed2[n] = vd;
    }
}

// ---------------- Layer-2 edge pass: exp-free gather + fused pool·Wr ---------
// one block per bucket; half-wave per dst (8 dsts per half-wave)
__global__ void edge2_gather(const int* __restrict__ bcnt, const int* __restrict__ boff,
                             const uint_t* __restrict__ pk,
                             const uint_t* __restrict__ sp2, const float* __restrict__ ed2,
                             const ushort_t* __restrict__ h2,
                             const float* __restrict__ b2, const float* __restrict__ Wr,
                             float* __restrict__ pooled, int N) {
    int b = blockIdx.x;
    int d0 = b << SHIFT;
    int cnt = bcnt[b];
    int gbase = boff[b];
    int tid = threadIdx.x;
    int hw = tid >> 5;  // 0..7
    int j = tid & 31;
    __shared__ int ldeg[BW];
    __shared__ int loff[BW];
    __shared__ int lcur[BW];
    __shared__ int lsrc[CAP];
    float wr = Wr[j];
    float b2w = b2[j] * wr;
    float part = 0.f;
    if (cnt <= CAP) {
        if (tid < BW) ldeg[tid] = 0;
        __syncthreads();
        for (int k = tid; k < cnt; k += 256) atomicAdd(&ldeg[pk[gbase + k] & (BW - 1)], 1);
        __syncthreads();
        if (tid < 64) {
            int v = ldeg[tid];
            int e = v;
#pragma unroll
            for (int o = 1; o < 64; o <<= 1) {
                int u = __shfl_up(e, o, 64);
                if (tid >= o) e += u;
            }
            e -= v;
            loff[tid] = e;
            lcur[tid] = e;
        }
        __syncthreads();
        for (int k = tid; k < cnt; k += 256) {
            uint_t v = pk[gbase + k];
            int pos = atomicAdd(&lcur[v & (BW - 1)], 1);
            lsrc[pos] = (int)(v >> SHIFT);
        }
        __syncthreads();
        for (int ld = hw * 8; ld < hw * 8 + 8; ++ld) {
            int d = d0 + ld;
            if (d >= N) break;
            int st = loff[ld], dg = ldeg[ld];
            float edv = ed2[d];
            float Ad = __expf(edv), Bd = __expf(NEG_SLOPE * edv);
            float acc = 0.f, wsum = 0.f;
#pragma unroll 4
            for (int k = st; k < st + dg; ++k) {
                int s = lsrc[k];
                uint_t u = sp2[s];
                float w = fmaxf(__uint_as_float(u << 16) * Ad,
                                __uint_as_float(u & 0xffff0000u) * Bd);
                acc = fmaf(w, bf2f(h2[(size_t)s * F2 + j]), acc);
                wsum += w;
            }
            part = fmaf(acc / wsum, wr, part + b2w);
        }
    } else {
        for (int ld = hw * 8; ld < hw * 8 + 8; ++ld) {
            int d = d0 + ld;
            if (d >= N) break;
            float edv = ed2[d];
            float Ad = __expf(edv), Bd = __expf(NEG_SLOPE * edv);
            float acc = 0.f, wsum = 0.f;
            for (int k = 0; k < cnt; ++k) {
                uint_t v = pk[gbase + k];
                if ((int)(v & (BW - 1)) != ld) continue;
                int s = (int)(v >> SHIFT);
                uint_t u = sp2[s];
                float w = fmaxf(__uint_as_float(u << 16) * Ad,
                                __uint_as_float(u & 0xffff0000u) * Bd);
                acc = fmaf(w, bf2f(h2[(size_t)s * F2 + j]), acc);
                wsum += w;
            }
            part = fmaf(acc / wsum, wr, part + b2w);
        }
    }
    // block reduction -> one atomic
#pragma unroll
    for (int o = 32; o >= 1; o >>= 1) part += __shfl_down(part, o, 64);
    __shared__ float ls[4];
    int wave = tid >> 6;
    if ((tid & 63) == 0) ls[wave] = part;
    __syncthreads();
    if (tid == 0) atomicAdd(pooled, ls[0] + ls[1] + ls[2] + ls[3]);
}

__global__ void final_kernel(const float* __restrict__ pooled, const float* __restrict__ br,
                             float* __restrict__ out) {
    if (threadIdx.x == 0 && blockIdx.x == 0) out[0] = pooled[0] + br[0];
}

extern "C" void kernel_launch(void* const* d_in, const int* in_sizes, int n_in,
                              void* d_out, int out_size, void* d_ws, size_t ws_size,
                              hipStream_t stream) {
    const float* x    = (const float*)d_in[0];
    const int*   ei   = (const int*)d_in[1];
    const float* W1   = (const float*)d_in[2];
    const float* a_s1 = (const float*)d_in[3];
    const float* a_d1 = (const float*)d_in[4];
    const float* b1   = (const float*)d_in[5];
    const float* W2   = (const float*)d_in[6];
    const float* a_s2 = (const float*)d_in[7];
    const float* a_d2 = (const float*)d_in[8];
    const float* b2   = (const float*)d_in[9];
    const float* Wr   = (const float*)d_in[10];
    const float* br   = (const float*)d_in[11];
    float* out = (float*)d_out;

    int N = in_sizes[0] / FIN;
    int E = in_sizes[1] / 2;
    size_t n = (size_t)N;
    int NB = (N + BW - 1) >> SHIFT;

    // workspace layout (bytes), total ~= 58 MB for N=100k, E=3.2M
    // (identical footprint to round 4: sp replaces es, same 32N bytes)
    char* ws = (char*)d_ws;
    float*    o1   = (float*)ws;                          // 64N f32
    uint_t*   sp1  = (uint_t*)(ws + n * 256);             // 8N u32 (bf16x2 exp table)
    float*    ed1  = (float*)(ws + n * 288);              // 8N f32
    ushort_t* h1   = (ushort_t*)(ws + n * 320);           // 64N bf16
    uint_t*   pk   = (uint_t*)(ws + n * 448);             // (E+N) uint
    char*     tail = ws + n * 448 + (size_t)(E + N) * 4;
    int*      bcnt = (int*)tail;                          // NBMAX int
    int*      boff = (int*)(tail + NBMAX * 4);            // NBMAX int
    int*      bcur = (int*)(tail + NBMAX * 8);            // NBMAX int
    float*  pooled = (float*)(tail + NBMAX * 12);         // 1 f32
    // layer-2 overlays (regions dead after edge1):
    ushort_t* h2  = h1;              // 32N bf16
    uint_t*   sp2 = sp1;             // N u32
    float*    ed2 = ed1;             // N f32

    zerob_kernel<<<8, 256, 0, stream>>>(bcnt, NB, pooled);
    gemm1_kernel<<<(N + 3) / 4, 256, 0, stream>>>(x, W1, a_s1, a_d1, h1, sp1, ed1, N);
    bhist_kernel<<<256, 256, 0, stream>>>(ei, E, N, bcnt, NB);
    bscan_kernel<<<1, 64, 0, stream>>>(bcnt, NB, boff, bcur);
    bscat_kernel<<<256, 256, 0, stream>>>(ei, E, N, bcur, pk, NB);
    edge1_gather<<<NB, 256, 0, stream>>>(bcnt, boff, pk, sp1, ed1, h1, o1, N);
    gemm2_kernel<<<(N + 7) / 8, 256, 0, stream>>>(o1, b1, W2, a_s2, a_d2, h2, sp2, ed2, N);
    edge2_gather<<<NB, 256, 0, stream>>>(bcnt, boff, pk, sp2, ed2, h2, b2, Wr, pooled, N);
    final_kernel<<<1, 64, 0, stream>>>(pooled, br, out);
}